// Round 19
// baseline (211.214 us; speedup 1.0000x reference)
//
#include <hip/hip_runtime.h>
#include <math.h>

// Banyan compose: phase-1 schedule construction + phase-2 CE replay, all on device.
// Sizes: B=64, L=64, E=256, CH=16. V=30000. Node ids < 8192.
// Phase 1: (a) 64 parallel per-row tree builds (single wave/row — frozen),
// (b) one-wave CAS-dedup id assignment, (c) parallel scatter.
// Phase 2: bf16 MFMA logits GEMM, defer-max online logsumexp (THR=32),
// LOG2E folded into A-side bf16.
// r19 loss geometry: M=128/block, ONE shared 16-col LDS tile per step
// (staged once per block — fixes the redundant-stream failure of the
// pre-staging M=128 attempts), double-buffered, 63x16 grid.

#define NMAX 8192
#define PRES 30720
#define HBITS 13
#define HSIZE 8192
#define HMASK 8191
#define LOG2E 1.44269504f
#define LN2 0.69314718f
#define NSLAB 16

typedef float f32x4 __attribute__((ext_vector_type(4)));
typedef short short8 __attribute__((ext_vector_type(8)));

__device__ __forceinline__ unsigned hash0(int key) {
    return (((unsigned)key) * 2654435761u) >> (32 - HBITS);
}

__device__ __forceinline__ unsigned short f2bf(float f) {
    unsigned u = __float_as_uint(f);
    unsigned r = ((u >> 16) & 1u) + 0x7FFFu;
    return (unsigned short)((u + r) >> 16);
}

__device__ __forceinline__ float rdl_f(float v, int lane) {
    return __int_as_float(__builtin_amdgcn_readlane(__float_as_int(v), lane));
}

#define SUM_STEP(CTRL, X) \
    X += __int_as_float(__builtin_amdgcn_update_dpp(0, __float_as_int(X), CTRL, 0xF, 0xF, true));
#define SUM3_REDUCE(A, B, C) {                                                  \
    SUM_STEP(0x121, A) SUM_STEP(0x121, B) SUM_STEP(0x121, C)                    \
    SUM_STEP(0x122, A) SUM_STEP(0x122, B) SUM_STEP(0x122, C)                    \
    SUM_STEP(0x124, A) SUM_STEP(0x124, B) SUM_STEP(0x124, C)                    \
    SUM_STEP(0x128, A) SUM_STEP(0x128, B) SUM_STEP(0x128, C)                    \
    A = rdl_f(A, 0) + rdl_f(A, 16) + rdl_f(A, 32) + rdl_f(A, 48);               \
    B = rdl_f(B, 0) + rdl_f(B, 16) + rdl_f(B, 32) + rdl_f(B, 48);               \
    C = rdl_f(C, 0) + rdl_f(C, 16) + rdl_f(C, 32) + rdl_f(C, 48);               \
}
#define ARGMAX_STEP(CTRL, V, I) {                                               \
    float _ov = __int_as_float(__builtin_amdgcn_update_dpp(0, __float_as_int(V), CTRL, 0xF, 0xF, true)); \
    int _oi = __builtin_amdgcn_update_dpp(0, I, CTRL, 0xF, 0xF, true);          \
    if (_ov > V || (_ov == V && _oi < I)) { V = _ov; I = _oi; }                 \
}
#define ARGMAX_REDUCE(V, I) {                                                   \
    ARGMAX_STEP(0x121, V, I) ARGMAX_STEP(0x122, V, I)                           \
    ARGMAX_STEP(0x124, V, I) ARGMAX_STEP(0x128, V, I)                           \
    float _v0 = rdl_f(V, 0), _v1 = rdl_f(V, 16), _v2 = rdl_f(V, 32), _v3 = rdl_f(V, 48); \
    int _i0 = __builtin_amdgcn_readlane(I, 0), _i1 = __builtin_amdgcn_readlane(I, 16);   \
    int _i2 = __builtin_amdgcn_readlane(I, 32), _i3 = __builtin_amdgcn_readlane(I, 48);  \
    V = _v0; I = _i0;                                                           \
    if (_v1 > V || (_v1 == V && _i1 < I)) { V = _v1; I = _i1; }                 \
    if (_v2 > V || (_v2 == V && _i2 < I)) { V = _v2; I = _i2; }                 \
    if (_v3 > V || (_v3 == V && _i3 < I)) { V = _v3; I = _i3; }                 \
}

// ---- fused setup: presence (LDS) + mark + shfl-scan + map, one block ----
__global__ __launch_bounds__(1024) void prep_kernel(
    const int* __restrict__ x, int* __restrict__ tokens,
    int* __restrict__ meta, int* __restrict__ index_g) {
    __shared__ int pres[PRES];
    __shared__ int part[1024];
    __shared__ int wsum[16];
    int tid = threadIdx.x;
    int lane = tid & 63, wave = tid >> 6;
    for (int i = tid; i < PRES; i += 1024) pres[i] = 0;
    __syncthreads();
    for (int i = tid; i < 4096; i += 1024) pres[x[i]] = 1;
    __syncthreads();
    int base = tid * 30;
    int loc[30];
    int tot = 0;
#pragma unroll
    for (int i = 0; i < 30; ++i) { loc[i] = tot; tot += pres[base + i]; }
    int sc = tot;
#pragma unroll
    for (int off = 1; off < 64; off <<= 1) {
        int v = __shfl_up(sc, off);
        if (lane >= off) sc += v;
    }
    if (lane == 63) wsum[wave] = sc;
    __syncthreads();
    if (tid < 16) {
        int wv = wsum[tid];
#pragma unroll
        for (int off = 1; off < 16; off <<= 1) {
            int v = __shfl_up(wv, off);
            if (tid >= off) wv += v;
        }
        wsum[tid] = wv;
    }
    __syncthreads();
    int incl = sc + ((wave == 0) ? 0 : wsum[wave - 1]);
    int excl = incl - tot;
    part[tid] = incl;
#pragma unroll
    for (int i = 0; i < 30; ++i) {
        if (pres[base + i]) tokens[excl + loc[i]] = base + i;
    }
    __syncthreads();
    int total = part[1023];
    if (tid == 0) { meta[0] = total; meta[1] = total - 1; }
#pragma unroll
    for (int i = 0; i < 30; ++i) pres[base + i] = excl + loc[i];
    __syncthreads();
    for (int i = tid; i < 4096; i += 1024) {
        int r = pres[x[i]];
        index_g[i] = (r == total - 1) ? -1 : r;
    }
}

// ---- fused: copy feats+norms (blocks 0..4095) | init cos (4096..8127) ----
__global__ __launch_bounds__(64) void prefeats_kernel(
    const float* __restrict__ emb, const int* __restrict__ tokens,
    const int* __restrict__ meta, const int* __restrict__ index_g,
    float* __restrict__ feats, float* __restrict__ norms,
    float* __restrict__ cos_g) {
    int g = blockIdx.x;
    int k = threadIdx.x;
    if (g < 4096) {
        int n = g;
        if (n >= meta[1]) return;
        int t = tokens[n];
        float4 v = ((const float4*)(emb + (size_t)t * 256))[k];
        ((float4*)(feats + (size_t)n * 256))[k] = v;
        float ss = v.x * v.x + v.y * v.y + v.z * v.z + v.w * v.w;
#pragma unroll
        for (int off = 32; off >= 1; off >>= 1) ss += __shfl_down(ss, off);
        if (k == 0) norms[n] = sqrtf(ss);
        return;
    }
    int idx = g - 4096;
    int b = idx / 63, j = idx % 63;
    int l = index_g[b * 64 + j], r = index_g[b * 64 + j + 1];
    float c = -INFINITY;
    if (r != -1) {
        int tl = tokens[l], tr = tokens[r];
        float4 a = ((const float4*)(emb + (size_t)tl * 256))[k];
        float4 bb = ((const float4*)(emb + (size_t)tr * 256))[k];
        float d = a.x * bb.x + a.y * bb.y + a.z * bb.z + a.w * bb.w;
        float na = a.x * a.x + a.y * a.y + a.z * a.z + a.w * a.w;
        float nb = bb.x * bb.x + bb.y * bb.y + bb.z * bb.z + bb.w * bb.w;
#pragma unroll
        for (int off = 32; off >= 1; off >>= 1) {
            d += __shfl_down(d, off);
            na += __shfl_down(na, off);
            nb += __shfl_down(nb, off);
        }
        c = d / fmaxf(sqrtf(na) * sqrtf(nb), 1e-8f);
    }
    if (k == 0) cos_g[b * 64 + j] = c;
}

// ---- pass 1: per-row tree build. 64 blocks x 1 wave, features in LDS. ----

__global__ __launch_bounds__(64) void treebuild_kernel(
    const float* __restrict__ feats, const float* __restrict__ norms_g,
    const int* __restrict__ index_g, const float* __restrict__ cos_g,
    float* __restrict__ rowfeats, int4* __restrict__ rec,
    const float* __restrict__ comp_l, const float* __restrict__ comp_r,
    const float* __restrict__ cb) {
    __shared__ float lf[127][256];
    __shared__ int4 s_rec[63];
    int b = blockIdx.x;
    int lane = threadIdx.x;
    int c0 = 4 * (lane & 3);
    float4 sl4 = make_float4(1.f / (1.f + __expf(-comp_l[c0])),
                             1.f / (1.f + __expf(-comp_l[c0 + 1])),
                             1.f / (1.f + __expf(-comp_l[c0 + 2])),
                             1.f / (1.f + __expf(-comp_l[c0 + 3])));
    float4 sr4 = make_float4(1.f / (1.f + __expf(-comp_r[c0])),
                             1.f / (1.f + __expf(-comp_r[c0 + 1])),
                             1.f / (1.f + __expf(-comp_r[c0 + 2])),
                             1.f / (1.f + __expf(-comp_r[c0 + 3])));
    float4 cb4 = make_float4(cb[c0], cb[c0 + 1], cb[c0 + 2], cb[c0 + 3]);

    int gid = index_g[b * 64 + lane];
    int isreal = (gid >= 0) ? 1 : 0;
    for (int j = 0; j < 64; ++j) {
        int g = index_g[b * 64 + j];
        int gc = g < 0 ? 0 : g;
        ((float4*)&lf[j][0])[lane] = ((const float4*)(feats + (size_t)gc * 256))[lane];
    }
    float n0 = (gid >= 0) ? norms_g[gid] : 0.f;
    float n1 = 0.f;
    float cosr = (lane < 63) ? cos_g[b * 64 + lane] : -INFINITY;
    int locid = lane;
    unsigned long long alive = ~0ull;
    int nreal = 64 - __popcll(__ballot(gid < 0));

    float Mv = cosr; int Mi = lane;
    ARGMAX_REDUCE(Mv, Mi);

    for (int it = 0; it < 63; ++it) {
        int act = (nreal >= 2) ? 1 : 0;
        int p = Mi;
        unsigned long long after = (alive >> 1) >> p;
        int q = (p + 1 + __builtin_ctzll(after | 0x8000000000000000ull)) & 63;
        unsigned long long bel = alive & ((1ull << p) - 1ull);
        int pp = bel ? (63 - __builtin_clzll(bel)) : -1;
        unsigned long long aft2 = (q < 63) ? (alive >> (q + 1)) : 0ull;
        int ssp = aft2 ? (q + 1 + __builtin_ctzll(aft2)) : -1;
        int l_loc = __builtin_amdgcn_readlane(locid, p);
        int r_loc = __builtin_amdgcn_readlane(locid, q);
        int lsl = __builtin_amdgcn_readlane(locid, pp < 0 ? 0 : pp);
        int rsl = __builtin_amdgcn_readlane(locid, ssp < 0 ? 0 : ssp);
        int ls_loc = (pp >= 0) ? lsl : -1;
        int rs_loc = (ssp >= 0) ? rsl : -2;
        int Creal = (ssp >= 0) ? __builtin_amdgcn_readlane(isreal, ssp) : 0;
        if (lane == 0)
            s_rec[it] = make_int4(act ? l_loc : -9, r_loc, ls_loc, rs_loc);
        if (act) {
            float4 a = ((const float4*)&lf[l_loc][0])[lane];
            float4 bb = ((const float4*)&lf[r_loc][0])[lane];
            float4 av = (pp >= 0) ? ((const float4*)&lf[ls_loc < 0 ? 0 : ls_loc][0])[lane]
                                  : make_float4(0.f, 0.f, 0.f, 0.f);
            float4 cv = Creal ? ((const float4*)&lf[rs_loc < 0 ? 0 : rs_loc][0])[lane]
                              : make_float4(0.f, 0.f, 0.f, 0.f);
            float mv = (lane == p || lane == q || lane == pp) ? -INFINITY : cosr;
            float Mv2 = mv; int Mi2 = lane;
            ARGMAX_REDUCE(Mv2, Mi2);
            int nl = 64 + it;
            float4 v;
            v.x = a.x * sl4.x + bb.x * sr4.x + cb4.x;
            v.y = a.y * sl4.y + bb.y * sr4.y + cb4.y;
            v.z = a.z * sl4.z + bb.z * sr4.z + cb4.z;
            v.w = a.w * sl4.w + bb.w * sr4.w + cb4.w;
            ((float4*)&lf[nl][0])[lane] = v;
            float sv = v.x * v.x + v.y * v.y + v.z * v.z + v.w * v.w;
            float da = av.x * v.x + av.y * v.y + av.z * v.z + av.w * v.w;
            float dc = cv.x * v.x + cv.y * v.y + cv.z * v.z + cv.w * v.w;
            SUM3_REDUCE(sv, da, dc);
            float nn = sqrtf(sv);
            if (lane == it) n1 = nn;
            float nA = 1.f, nC = 1.f;
            if (pp >= 0) nA = (ls_loc < 64) ? rdl_f(n0, ls_loc) : rdl_f(n1, ls_loc - 64);
            if (Creal)   nC = (rs_loc < 64) ? rdl_f(n0, rs_loc) : rdl_f(n1, rs_loc - 64);
            float cosA = da * __builtin_amdgcn_rcpf(fmaxf(nA * nn, 1e-8f));
            float cosC = Creal ? (dc * __builtin_amdgcn_rcpf(fmaxf(nn * nC, 1e-8f))) : -INFINITY;
            if (lane == p) { cosr = cosC; locid = nl; }
            if (lane == pp) cosr = cosA;
            if (lane == q) cosr = -INFINITY;
            if (pp >= 0 && (cosA > Mv2 || (cosA == Mv2 && pp < Mi2))) { Mv2 = cosA; Mi2 = pp; }
            if (cosC > Mv2 || (cosC == Mv2 && p < Mi2)) { Mv2 = cosC; Mi2 = p; }
            Mv = Mv2; Mi = Mi2;
            alive &= ~(1ull << q);
            nreal -= 1;
        }
    }
    for (int it = 0; it < 63; ++it) {
        ((float4*)(rowfeats + ((size_t)b * 63 + it) * 256))[lane] =
            ((const float4*)&lf[64 + it][0])[lane];
    }
    if (lane < 63) rec[b * 63 + lane] = s_rec[lane];
}

// ---- pass 2: one-wave id assignment (CAS-probe dedup, arbitrary id order) ----

__global__ __launch_bounds__(64) void idassign_kernel(
    const int4* __restrict__ rec, const int* __restrict__ index_g,
    int* __restrict__ targets, int* __restrict__ meta, int* __restrict__ newsrc) {
    __shared__ int s_map[64][128];
    __shared__ int s_hk[HSIZE], s_hv[HSIZE];
    int b = threadIdx.x;
    for (int i = b; i < HSIZE; i += 64) s_hk[i] = -1;
    for (int i = b; i < 4096; i += 64) s_map[i >> 6][i & 63] = index_g[i];
    int N0 = meta[1];
    int Ncur = N0, Tcur = 0;
    __syncthreads();
    int4 R = rec[b * 63];
    for (int it = 0; it < 63; ++it) {
        int4 Rn = R;
        if (it + 1 < 63) Rn = rec[b * 63 + it + 1];
        int act = (R.x != -9) ? 1 : 0;
        int l_g = 0, r_g = 0, key = 0, nid = 0;
        int ls_g = -1, rs_g = -2;
        unsigned h = 0;
        int won = 0, need = 0;
        if (act) {
            l_g = s_map[b][R.x];
            r_g = s_map[b][R.y];
            ls_g = (R.z >= 0) ? s_map[b][R.z] : R.z;
            rs_g = (R.w >= 0) ? s_map[b][R.w] : R.w;
            key = (l_g << HBITS) | r_g;
            h = hash0(key);
            need = 1;
        }
        while (__any(need)) {
            if (need) {
                int prev = atomicCAS(&s_hk[h], -1, key);
                if (prev == -1) { won = 1; need = 0; }
                else if (prev == key) { need = 0; }
                else { h = (h + 1) & HMASK; }
            }
        }
        unsigned long long actmask = __ballot(act != 0);
        unsigned long long winmask = __ballot(won != 0);
        unsigned long long below = (1ull << b) - 1ull;
        int ar = __popcll(actmask & below);
        int nact = __popcll(actmask);
        int newc = __popcll(winmask);
        if (won) {
            nid = Ncur + __popcll(winmask & below);
            s_hv[h] = nid;
        }
        __syncthreads();
        if (act && !won) nid = s_hv[h];
        if (won) newsrc[nid - N0] = (b << 6) | it;
        if (act) {
            int o1 = Tcur + ar;
            targets[o1 * 3 + 0] = l_g;
            targets[o1 * 3 + 1] = ls_g;
            targets[o1 * 3 + 2] = r_g;
            int o2 = Tcur + nact + ar;
            targets[o2 * 3 + 0] = r_g;
            targets[o2 * 3 + 1] = l_g;
            targets[o2 * 3 + 2] = rs_g;
            s_map[b][64 + it] = nid;
        }
        Ncur += newc;
        Tcur += 2 * nact;
        R = Rn;
    }
    if (b == 0) { meta[2] = Ncur; meta[3] = Tcur; meta[4] = Ncur - N0; }
}

// ---- pass 3: scatter composed rows + append eos/sos (block 4032) ----

__global__ __launch_bounds__(64) void materialize_kernel(
    const float* __restrict__ rowfeats, const int* __restrict__ newsrc,
    const int* __restrict__ meta, float* __restrict__ feats,
    const float* __restrict__ eos, const float* __restrict__ sos) {
    int g = blockIdx.x;
    int lane = threadIdx.x;
    if (g == 4032) {
        int n = meta[2];
        ((float4*)(feats + (size_t)n * 256))[lane] = ((const float4*)eos)[lane];
        ((float4*)(feats + (size_t)(n + 1) * 256))[lane] = ((const float4*)sos)[lane];
        return;
    }
    if (g >= meta[4]) return;
    int pk = newsrc[g];
    int b = pk >> 6, it = pk & 63;
    int N0 = meta[1];
    ((float4*)(feats + (size_t)(N0 + g) * 256))[lane] =
        ((const float4*)(rowfeats + ((size_t)b * 63 + it) * 256))[lane];
}

// ---- fused: bf16 fragment-major convert (blocks 0..1023) | out rows +
// target logits (blocks 1024..3039) ----
__global__ __launch_bounds__(256) void convout_kernel(
    const float* __restrict__ feats, const int* __restrict__ targets,
    const int* __restrict__ meta, const float* __restrict__ comp_l,
    const float* __restrict__ comp_r, const float* __restrict__ cb,
    short8* __restrict__ fhT, unsigned short* __restrict__ oh,
    float* __restrict__ tdot) {
    if (blockIdx.x < 1024) {
        int g = blockIdx.x * 256 + threadIdx.x;
        int tile = g >> 9, rem = g & 511;
        int ks = rem >> 6, lane64 = rem & 63;
        int kq = lane64 >> 4, col = lane64 & 15;
        int row = tile * 16 + col;
        int e0 = (ks * 4 + kq) * 8;
        const float4* src = (const float4*)(feats + (size_t)row * 256 + e0);
        float4 v0 = src[0], v1 = src[1];
        short8 o;
        o[0] = (short)f2bf(v0.x); o[1] = (short)f2bf(v0.y);
        o[2] = (short)f2bf(v0.z); o[3] = (short)f2bf(v0.w);
        o[4] = (short)f2bf(v1.x); o[5] = (short)f2bf(v1.y);
        o[6] = (short)f2bf(v1.z); o[7] = (short)f2bf(v1.w);
        fhT[g] = o;
        return;
    }
    int T = meta[3];
    int Ntot = meta[2] + 2;
    int t = (blockIdx.x - 1024) * 4 + (threadIdx.x >> 6);
    if (t >= T) return;
    int lane = threadIdx.x & 63;
    int c0 = 4 * (lane & 3);
    float4 sl4 = make_float4(1.f / (1.f + __expf(-comp_l[c0])),
                             1.f / (1.f + __expf(-comp_l[c0 + 1])),
                             1.f / (1.f + __expf(-comp_l[c0 + 2])),
                             1.f / (1.f + __expf(-comp_l[c0 + 3])));
    float4 sr4 = make_float4(1.f / (1.f + __expf(-comp_r[c0])),
                             1.f / (1.f + __expf(-comp_r[c0 + 1])),
                             1.f / (1.f + __expf(-comp_r[c0 + 2])),
                             1.f / (1.f + __expf(-comp_r[c0 + 3])));
    float4 cb4 = make_float4(cb[c0], cb[c0 + 1], cb[c0 + 2], cb[c0 + 3]);
    int t0 = targets[t * 3 + 0];
    int i1 = targets[t * 3 + 1], i2 = targets[t * 3 + 2];
    if (i1 < 0) i1 += Ntot;
    if (i2 < 0) i2 += Ntot;
    float4 a = ((const float4*)(feats + (size_t)i1 * 256))[lane];
    float4 b = ((const float4*)(feats + (size_t)i2 * 256))[lane];
    float4 ft = ((const float4*)(feats + (size_t)t0 * 256))[lane];
    float4 v;
    v.x = a.x * sl4.x + b.x * sr4.x + cb4.x;
    v.y = a.y * sl4.y + b.y * sr4.y + cb4.y;
    v.z = a.z * sl4.z + b.z * sr4.z + cb4.z;
    v.w = a.w * sl4.w + b.w * sr4.w + cb4.w;
    float d = v.x * ft.x + v.y * ft.y + v.z * ft.z + v.w * ft.w;
#pragma unroll
    for (int off = 32; off >= 1; off >>= 1) d += __shfl_down(d, off);
    if (lane == 0) tdot[t] = d;
    ushort4 h;
    h.x = f2bf(v.x * LOG2E); h.y = f2bf(v.y * LOG2E);
    h.z = f2bf(v.z * LOG2E); h.w = f2bf(v.w * LOG2E);
    ((ushort4*)(oh + (size_t)t * 256))[lane] = h;
}

// ---- loss: M=128/block (8 waves x 16 rows), ONE shared 16-col LDS tile per
// step, double-buffered (1 barrier/step); defer-max (THR=32); 63 x NSLAB grid;
// direct per-row partial writes (no epilogue LDS merge). ----
__global__ __launch_bounds__(512) void loss_mfma_kernel(
    const short8* __restrict__ fhT, const unsigned short* __restrict__ oh,
    const int* __restrict__ meta, float2* __restrict__ partial) {
    __shared__ short8 lds_b[2][512];       // 2 x 8 KB
    int T = meta[3];
    int Ntot = meta[2] + 2;
    int row0 = blockIdx.x * 128;
    if (row0 >= T) return;
    int slab = blockIdx.y;
    int P = (Ntot + 16 * NSLAB - 1) / (16 * NSLAB);   // 16-col steps per slab
    int cstart = slab * (P << 4);
    int cend = min(Ntot, cstart + (P << 4));
    int tid = threadIdx.x, lane = tid & 63, w = tid >> 6;
    int mrowb = row0 + w * 16;
    int mrow = mrowb + (lane & 15);
    int mrowc = min(mrow, T - 1);
    int kq = lane >> 4;
    const short8* pah = (const short8*)(oh + (size_t)mrowc * 256);
    short8 Ah[8];
#pragma unroll
    for (int ks = 0; ks < 8; ++ks) Ah[ks] = pah[ks * 4 + kq];
    float m0 = -1e30f, m1 = -1e30f, m2 = -1e30f, m3 = -1e30f;
    float s0 = 0.f, s1 = 0.f, s2 = 0.f, s3 = 0.f;
    int cur = 0;
    if (cstart < cend) {
        lds_b[0][tid] = fhT[(size_t)(cstart >> 4) * 512 + tid];
        __syncthreads();
    }
    for (int nb = cstart; nb < cend; nb += 16) {
        short8 g0;
        bool more = (nb + 16) < cend;
        if (more) g0 = fhT[(size_t)((nb + 16) >> 4) * 512 + tid];
        const short8* pb = lds_b[cur];
        f32x4 a0 = {0.f, 0.f, 0.f, 0.f}, a1 = a0;
#pragma unroll
        for (int ks = 0; ks < 4; ++ks) {
            a0 = __builtin_amdgcn_mfma_f32_16x16x32_bf16(Ah[ks], pb[ks * 64 + lane], a0, 0, 0, 0);
            a1 = __builtin_amdgcn_mfma_f32_16x16x32_bf16(Ah[ks + 4], pb[(ks + 4) * 64 + lane], a1, 0, 0, 0);
        }
        int col = nb + (lane & 15);
        bool cv = col < cend;
        float v0 = cv ? (a0[0] + a1[0]) : -INFINITY;   // log2-domain
        float v1 = cv ? (a0[1] + a1[1]) : -INFINITY;
        float v2 = cv ? (a0[2] + a1[2]) : -INFINITY;
        float v3 = cv ? (a0[3] + a1[3]) : -INFINITY;
        float d0 = v0 - m0, d1 = v1 - m1, d2 = v2 - m2, d3 = v3 - m3;
        if (d0 > 32.f) { s0 = s0 * exp2f(-d0) + 1.f; m0 = v0; } else s0 += exp2f(d0);
        if (d1 > 32.f) { s1 = s1 * exp2f(-d1) + 1.f; m1 = v1; } else s1 += exp2f(d1);
        if (d2 > 32.f) { s2 = s2 * exp2f(-d2) + 1.f; m2 = v2; } else s2 += exp2f(d2);
        if (d3 > 32.f) { s3 = s3 * exp2f(-d3) + 1.f; m3 = v3; } else s3 += exp2f(d3);
        if (more) {
            lds_b[cur ^ 1][tid] = g0;
            __syncthreads();
            cur ^= 1;
        }
    }
    // reduce over the 16 cols held by each kq group's lanes
#pragma unroll
    for (int off = 1; off < 16; off <<= 1) {
        float mo, so, mn;
        mo = __shfl_xor(m0, off); so = __shfl_xor(s0, off);
        mn = fmaxf(m0, mo); s0 = s0 * exp2f(m0 - mn) + so * exp2f(mo - mn); m0 = mn;
        mo = __shfl_xor(m1, off); so = __shfl_xor(s1, off);
        mn = fmaxf(m1, mo); s1 = s1 * exp2f(m1 - mn) + so * exp2f(mo - mn); m1 = mn;
        mo = __shfl_xor(m2, off); so = __shfl_xor(s2, off);
        mn = fmaxf(m2, mo); s2 = s2 * exp2f(m2 - mn) + so * exp2f(mo - mn); m2 = mn;
        mo = __shfl_xor(m3, off); so = __shfl_xor(s3, off);
        mn = fmaxf(m3, mo); s3 = s3 * exp2f(m3 - mn) + so * exp2f(mo - mn); m3 = mn;
    }
    if ((lane & 15) == 0) {
        int rb = mrowb + kq * 4;
        if (rb + 0 < T) partial[(size_t)slab * NMAX + rb + 0] = make_float2(m0, s0);
        if (rb + 1 < T) partial[(size_t)slab * NMAX + rb + 1] = make_float2(m1, s1);
        if (rb + 2 < T) partial[(size_t)slab * NMAX + rb + 2] = make_float2(m2, s2);
        if (rb + 3 < T) partial[(size_t)slab * NMAX + rb + 3] = make_float2(m3, s3);
    }
}

// ---- combine + finalize: one block, no atomics ----
__global__ __launch_bounds__(1024) void combine_kernel(
    const float2* __restrict__ partial, const float* __restrict__ tdot,
    const int* __restrict__ meta, float* __restrict__ out) {
    __shared__ float red[16];
    int T = meta[3];
    float loss = 0.f;
    for (int r = threadIdx.x; r < T; r += 1024) {
        float2 ps[NSLAB];
        float mn = -1e30f;
#pragma unroll
        for (int s = 0; s < NSLAB; ++s) {
            ps[s] = partial[(size_t)s * NMAX + r];
            mn = fmaxf(mn, ps[s].x);
        }
        float ss = 0.f;
#pragma unroll
        for (int s = 0; s < NSLAB; ++s) ss += ps[s].y * exp2f(ps[s].x - mn);
        loss += (mn + __log2f(ss)) * LN2 - tdot[r];
    }
#pragma unroll
    for (int off = 32; off >= 1; off >>= 1) loss += __shfl_down(loss, off);
    if ((threadIdx.x & 63) == 0) red[threadIdx.x >> 6] = loss;
    __syncthreads();
    if (threadIdx.x < 16) {
        loss = red[threadIdx.x];
#pragma unroll
        for (int off = 8; off >= 1; off >>= 1) loss += __shfl_down(loss, off);
        if (threadIdx.x == 0) out[0] = loss / (float)T;
    }
}

extern "C" void kernel_launch(void* const* d_in, const int* in_sizes, int n_in,
                              void* d_out, int out_size, void* d_ws, size_t ws_size,
                              hipStream_t stream) {
    const int* x = (const int*)d_in[0];
    const float* emb = (const float*)d_in[1];
    const float* comp_l = (const float*)d_in[2];
    const float* comp_r = (const float*)d_in[3];
    const float* cb = (const float*)d_in[4];
    const float* sos = (const float*)d_in[5];
    const float* eos = (const float*)d_in[6];
    float* out = (float*)d_out;

    float* feats = (float*)d_ws;                   // 8192*256
    float* norms = feats + (size_t)NMAX * 256;     // 8192
    int* index_g = (int*)(norms + NMAX);           // 4096
    float* cos_g = (float*)(index_g + 4096);       // 4096
    int* tokens = (int*)(cos_g + 4096);            // 4096
    int* targets = tokens + 4096;                  // 8192*3
    int* meta = targets + NMAX * 3;                // 64
    float* tdot = (float*)(meta + 64);             // 8192
    float2* partial = (float2*)(tdot + NMAX);      // NSLAB*8192 float2
    int4* rec = (int4*)(partial + NSLAB * NMAX);   // 64*63 int4
    int* newsrc = (int*)(rec + 64 * 63);           // 4096
    float* rowfeats = (float*)(newsrc + 4096);     // 64*63*256
    short8* fhT = (short8*)(rowfeats + (size_t)64 * 63 * 256);   // NMAX*32 short8
    unsigned short* oh = (unsigned short*)(fhT + (size_t)NMAX * 32);

    prep_kernel<<<1, 1024, 0, stream>>>(x, tokens, meta, index_g);
    prefeats_kernel<<<8128, 64, 0, stream>>>(emb, tokens, meta, index_g,
                                             feats, norms, cos_g);
    treebuild_kernel<<<64, 64, 0, stream>>>(feats, norms, index_g, cos_g,
                                            rowfeats, rec, comp_l, comp_r, cb);
    idassign_kernel<<<1, 64, 0, stream>>>(rec, index_g, targets, meta, newsrc);
    materialize_kernel<<<4033, 64, 0, stream>>>(rowfeats, newsrc, meta, feats, eos, sos);
    convout_kernel<<<3040, 256, 0, stream>>>(feats, targets, meta, comp_l, comp_r,
                                             cb, fhT, oh, tdot);
    loss_mfma_kernel<<<dim3(63, NSLAB), 512, 0, stream>>>(fhT, oh, meta, partial);
    combine_kernel<<<1, 1024, 0, stream>>>(partial, tdot, meta, out);
}

// Round 20
// 197.587 us; speedup vs baseline: 1.0690x; 1.0690x over previous
//
#include <hip/hip_runtime.h>
#include <math.h>

// Banyan compose: phase-1 schedule construction + phase-2 CE replay, all on device.
// Sizes: B=64, L=64, E=256, CH=16. V=30000. Node ids < 8192.
// Phase 1: (a) 64 parallel per-row tree builds (single wave/row — frozen),
// (b) one-wave CAS-dedup id assignment, (c) parallel scatter.
// Phase 2: bf16 MFMA logits GEMM, defer-max online logsumexp (THR=32),
// LOG2E folded into A-side bf16. Loss geometry M=64/nq/126x8 — FROZEN:
// M=128 regressed three times (r11, r13, r19 — even LDS-staged; barrier-to-
// MFMA ratio doubles at 16-col steps). This file = r18 config (best: 197.8us).

#define NMAX 8192
#define PRES 30720
#define HBITS 13
#define HSIZE 8192
#define HMASK 8191
#define LOG2E 1.44269504f
#define LN2 0.69314718f
#define NSLAB 8

typedef float f32x4 __attribute__((ext_vector_type(4)));
typedef short short8 __attribute__((ext_vector_type(8)));

__device__ __forceinline__ unsigned hash0(int key) {
    return (((unsigned)key) * 2654435761u) >> (32 - HBITS);
}

__device__ __forceinline__ unsigned short f2bf(float f) {
    unsigned u = __float_as_uint(f);
    unsigned r = ((u >> 16) & 1u) + 0x7FFFu;
    return (unsigned short)((u + r) >> 16);
}

__device__ __forceinline__ float rdl_f(float v, int lane) {
    return __int_as_float(__builtin_amdgcn_readlane(__float_as_int(v), lane));
}

#define SUM_STEP(CTRL, X) \
    X += __int_as_float(__builtin_amdgcn_update_dpp(0, __float_as_int(X), CTRL, 0xF, 0xF, true));
#define SUM3_REDUCE(A, B, C) {                                                  \
    SUM_STEP(0x121, A) SUM_STEP(0x121, B) SUM_STEP(0x121, C)                    \
    SUM_STEP(0x122, A) SUM_STEP(0x122, B) SUM_STEP(0x122, C)                    \
    SUM_STEP(0x124, A) SUM_STEP(0x124, B) SUM_STEP(0x124, C)                    \
    SUM_STEP(0x128, A) SUM_STEP(0x128, B) SUM_STEP(0x128, C)                    \
    A = rdl_f(A, 0) + rdl_f(A, 16) + rdl_f(A, 32) + rdl_f(A, 48);               \
    B = rdl_f(B, 0) + rdl_f(B, 16) + rdl_f(B, 32) + rdl_f(B, 48);               \
    C = rdl_f(C, 0) + rdl_f(C, 16) + rdl_f(C, 32) + rdl_f(C, 48);               \
}
#define ARGMAX_STEP(CTRL, V, I) {                                               \
    float _ov = __int_as_float(__builtin_amdgcn_update_dpp(0, __float_as_int(V), CTRL, 0xF, 0xF, true)); \
    int _oi = __builtin_amdgcn_update_dpp(0, I, CTRL, 0xF, 0xF, true);          \
    if (_ov > V || (_ov == V && _oi < I)) { V = _ov; I = _oi; }                 \
}
#define ARGMAX_REDUCE(V, I) {                                                   \
    ARGMAX_STEP(0x121, V, I) ARGMAX_STEP(0x122, V, I)                           \
    ARGMAX_STEP(0x124, V, I) ARGMAX_STEP(0x128, V, I)                           \
    float _v0 = rdl_f(V, 0), _v1 = rdl_f(V, 16), _v2 = rdl_f(V, 32), _v3 = rdl_f(V, 48); \
    int _i0 = __builtin_amdgcn_readlane(I, 0), _i1 = __builtin_amdgcn_readlane(I, 16);   \
    int _i2 = __builtin_amdgcn_readlane(I, 32), _i3 = __builtin_amdgcn_readlane(I, 48);  \
    V = _v0; I = _i0;                                                           \
    if (_v1 > V || (_v1 == V && _i1 < I)) { V = _v1; I = _i1; }                 \
    if (_v2 > V || (_v2 == V && _i2 < I)) { V = _v2; I = _i2; }                 \
    if (_v3 > V || (_v3 == V && _i3 < I)) { V = _v3; I = _i3; }                 \
}

// ---- fused setup: presence (LDS) + mark + shfl-scan + map, one block ----
__global__ __launch_bounds__(1024) void prep_kernel(
    const int* __restrict__ x, int* __restrict__ tokens,
    int* __restrict__ meta, int* __restrict__ index_g) {
    __shared__ int pres[PRES];
    __shared__ int part[1024];
    __shared__ int wsum[16];
    int tid = threadIdx.x;
    int lane = tid & 63, wave = tid >> 6;
    for (int i = tid; i < PRES; i += 1024) pres[i] = 0;
    __syncthreads();
    for (int i = tid; i < 4096; i += 1024) pres[x[i]] = 1;
    __syncthreads();
    int base = tid * 30;
    int loc[30];
    int tot = 0;
#pragma unroll
    for (int i = 0; i < 30; ++i) { loc[i] = tot; tot += pres[base + i]; }
    int sc = tot;
#pragma unroll
    for (int off = 1; off < 64; off <<= 1) {
        int v = __shfl_up(sc, off);
        if (lane >= off) sc += v;
    }
    if (lane == 63) wsum[wave] = sc;
    __syncthreads();
    if (tid < 16) {
        int wv = wsum[tid];
#pragma unroll
        for (int off = 1; off < 16; off <<= 1) {
            int v = __shfl_up(wv, off);
            if (tid >= off) wv += v;
        }
        wsum[tid] = wv;
    }
    __syncthreads();
    int incl = sc + ((wave == 0) ? 0 : wsum[wave - 1]);
    int excl = incl - tot;
    part[tid] = incl;
#pragma unroll
    for (int i = 0; i < 30; ++i) {
        if (pres[base + i]) tokens[excl + loc[i]] = base + i;
    }
    __syncthreads();
    int total = part[1023];
    if (tid == 0) { meta[0] = total; meta[1] = total - 1; }
#pragma unroll
    for (int i = 0; i < 30; ++i) pres[base + i] = excl + loc[i];
    __syncthreads();
    for (int i = tid; i < 4096; i += 1024) {
        int r = pres[x[i]];
        index_g[i] = (r == total - 1) ? -1 : r;
    }
}

// ---- fused: copy feats+norms (blocks 0..4095) | init cos (4096..8127) ----
__global__ __launch_bounds__(64) void prefeats_kernel(
    const float* __restrict__ emb, const int* __restrict__ tokens,
    const int* __restrict__ meta, const int* __restrict__ index_g,
    float* __restrict__ feats, float* __restrict__ norms,
    float* __restrict__ cos_g) {
    int g = blockIdx.x;
    int k = threadIdx.x;
    if (g < 4096) {
        int n = g;
        if (n >= meta[1]) return;
        int t = tokens[n];
        float4 v = ((const float4*)(emb + (size_t)t * 256))[k];
        ((float4*)(feats + (size_t)n * 256))[k] = v;
        float ss = v.x * v.x + v.y * v.y + v.z * v.z + v.w * v.w;
#pragma unroll
        for (int off = 32; off >= 1; off >>= 1) ss += __shfl_down(ss, off);
        if (k == 0) norms[n] = sqrtf(ss);
        return;
    }
    int idx = g - 4096;
    int b = idx / 63, j = idx % 63;
    int l = index_g[b * 64 + j], r = index_g[b * 64 + j + 1];
    float c = -INFINITY;
    if (r != -1) {
        int tl = tokens[l], tr = tokens[r];
        float4 a = ((const float4*)(emb + (size_t)tl * 256))[k];
        float4 bb = ((const float4*)(emb + (size_t)tr * 256))[k];
        float d = a.x * bb.x + a.y * bb.y + a.z * bb.z + a.w * bb.w;
        float na = a.x * a.x + a.y * a.y + a.z * a.z + a.w * a.w;
        float nb = bb.x * bb.x + bb.y * bb.y + bb.z * bb.z + bb.w * bb.w;
#pragma unroll
        for (int off = 32; off >= 1; off >>= 1) {
            d += __shfl_down(d, off);
            na += __shfl_down(na, off);
            nb += __shfl_down(nb, off);
        }
        c = d / fmaxf(sqrtf(na) * sqrtf(nb), 1e-8f);
    }
    if (k == 0) cos_g[b * 64 + j] = c;
}

// ---- pass 1: per-row tree build. 64 blocks x 1 wave, features in LDS. ----

__global__ __launch_bounds__(64) void treebuild_kernel(
    const float* __restrict__ feats, const float* __restrict__ norms_g,
    const int* __restrict__ index_g, const float* __restrict__ cos_g,
    float* __restrict__ rowfeats, int4* __restrict__ rec,
    const float* __restrict__ comp_l, const float* __restrict__ comp_r,
    const float* __restrict__ cb) {
    __shared__ float lf[127][256];
    __shared__ int4 s_rec[63];
    int b = blockIdx.x;
    int lane = threadIdx.x;
    int c0 = 4 * (lane & 3);
    float4 sl4 = make_float4(1.f / (1.f + __expf(-comp_l[c0])),
                             1.f / (1.f + __expf(-comp_l[c0 + 1])),
                             1.f / (1.f + __expf(-comp_l[c0 + 2])),
                             1.f / (1.f + __expf(-comp_l[c0 + 3])));
    float4 sr4 = make_float4(1.f / (1.f + __expf(-comp_r[c0])),
                             1.f / (1.f + __expf(-comp_r[c0 + 1])),
                             1.f / (1.f + __expf(-comp_r[c0 + 2])),
                             1.f / (1.f + __expf(-comp_r[c0 + 3])));
    float4 cb4 = make_float4(cb[c0], cb[c0 + 1], cb[c0 + 2], cb[c0 + 3]);

    int gid = index_g[b * 64 + lane];
    int isreal = (gid >= 0) ? 1 : 0;
    for (int j = 0; j < 64; ++j) {
        int g = index_g[b * 64 + j];
        int gc = g < 0 ? 0 : g;
        ((float4*)&lf[j][0])[lane] = ((const float4*)(feats + (size_t)gc * 256))[lane];
    }
    float n0 = (gid >= 0) ? norms_g[gid] : 0.f;
    float n1 = 0.f;
    float cosr = (lane < 63) ? cos_g[b * 64 + lane] : -INFINITY;
    int locid = lane;
    unsigned long long alive = ~0ull;
    int nreal = 64 - __popcll(__ballot(gid < 0));

    float Mv = cosr; int Mi = lane;
    ARGMAX_REDUCE(Mv, Mi);

    for (int it = 0; it < 63; ++it) {
        int act = (nreal >= 2) ? 1 : 0;
        int p = Mi;
        unsigned long long after = (alive >> 1) >> p;
        int q = (p + 1 + __builtin_ctzll(after | 0x8000000000000000ull)) & 63;
        unsigned long long bel = alive & ((1ull << p) - 1ull);
        int pp = bel ? (63 - __builtin_clzll(bel)) : -1;
        unsigned long long aft2 = (q < 63) ? (alive >> (q + 1)) : 0ull;
        int ssp = aft2 ? (q + 1 + __builtin_ctzll(aft2)) : -1;
        int l_loc = __builtin_amdgcn_readlane(locid, p);
        int r_loc = __builtin_amdgcn_readlane(locid, q);
        int lsl = __builtin_amdgcn_readlane(locid, pp < 0 ? 0 : pp);
        int rsl = __builtin_amdgcn_readlane(locid, ssp < 0 ? 0 : ssp);
        int ls_loc = (pp >= 0) ? lsl : -1;
        int rs_loc = (ssp >= 0) ? rsl : -2;
        int Creal = (ssp >= 0) ? __builtin_amdgcn_readlane(isreal, ssp) : 0;
        if (lane == 0)
            s_rec[it] = make_int4(act ? l_loc : -9, r_loc, ls_loc, rs_loc);
        if (act) {
            float4 a = ((const float4*)&lf[l_loc][0])[lane];
            float4 bb = ((const float4*)&lf[r_loc][0])[lane];
            float4 av = (pp >= 0) ? ((const float4*)&lf[ls_loc < 0 ? 0 : ls_loc][0])[lane]
                                  : make_float4(0.f, 0.f, 0.f, 0.f);
            float4 cv = Creal ? ((const float4*)&lf[rs_loc < 0 ? 0 : rs_loc][0])[lane]
                              : make_float4(0.f, 0.f, 0.f, 0.f);
            float mv = (lane == p || lane == q || lane == pp) ? -INFINITY : cosr;
            float Mv2 = mv; int Mi2 = lane;
            ARGMAX_REDUCE(Mv2, Mi2);
            int nl = 64 + it;
            float4 v;
            v.x = a.x * sl4.x + bb.x * sr4.x + cb4.x;
            v.y = a.y * sl4.y + bb.y * sr4.y + cb4.y;
            v.z = a.z * sl4.z + bb.z * sr4.z + cb4.z;
            v.w = a.w * sl4.w + bb.w * sr4.w + cb4.w;
            ((float4*)&lf[nl][0])[lane] = v;
            float sv = v.x * v.x + v.y * v.y + v.z * v.z + v.w * v.w;
            float da = av.x * v.x + av.y * v.y + av.z * v.z + av.w * v.w;
            float dc = cv.x * v.x + cv.y * v.y + cv.z * v.z + cv.w * v.w;
            SUM3_REDUCE(sv, da, dc);
            float nn = sqrtf(sv);
            if (lane == it) n1 = nn;
            float nA = 1.f, nC = 1.f;
            if (pp >= 0) nA = (ls_loc < 64) ? rdl_f(n0, ls_loc) : rdl_f(n1, ls_loc - 64);
            if (Creal)   nC = (rs_loc < 64) ? rdl_f(n0, rs_loc) : rdl_f(n1, rs_loc - 64);
            float cosA = da * __builtin_amdgcn_rcpf(fmaxf(nA * nn, 1e-8f));
            float cosC = Creal ? (dc * __builtin_amdgcn_rcpf(fmaxf(nn * nC, 1e-8f))) : -INFINITY;
            if (lane == p) { cosr = cosC; locid = nl; }
            if (lane == pp) cosr = cosA;
            if (lane == q) cosr = -INFINITY;
            if (pp >= 0 && (cosA > Mv2 || (cosA == Mv2 && pp < Mi2))) { Mv2 = cosA; Mi2 = pp; }
            if (cosC > Mv2 || (cosC == Mv2 && p < Mi2)) { Mv2 = cosC; Mi2 = p; }
            Mv = Mv2; Mi = Mi2;
            alive &= ~(1ull << q);
            nreal -= 1;
        }
    }
    for (int it = 0; it < 63; ++it) {
        ((float4*)(rowfeats + ((size_t)b * 63 + it) * 256))[lane] =
            ((const float4*)&lf[64 + it][0])[lane];
    }
    if (lane < 63) rec[b * 63 + lane] = s_rec[lane];
}

// ---- pass 2: one-wave id assignment (CAS-probe dedup, arbitrary id order) ----

__global__ __launch_bounds__(64) void idassign_kernel(
    const int4* __restrict__ rec, const int* __restrict__ index_g,
    int* __restrict__ targets, int* __restrict__ meta, int* __restrict__ newsrc) {
    __shared__ int s_map[64][128];
    __shared__ int s_hk[HSIZE], s_hv[HSIZE];
    int b = threadIdx.x;
    for (int i = b; i < HSIZE; i += 64) s_hk[i] = -1;
    for (int i = b; i < 4096; i += 64) s_map[i >> 6][i & 63] = index_g[i];
    int N0 = meta[1];
    int Ncur = N0, Tcur = 0;
    __syncthreads();
    int4 R = rec[b * 63];
    for (int it = 0; it < 63; ++it) {
        int4 Rn = R;
        if (it + 1 < 63) Rn = rec[b * 63 + it + 1];
        int act = (R.x != -9) ? 1 : 0;
        int l_g = 0, r_g = 0, key = 0, nid = 0;
        int ls_g = -1, rs_g = -2;
        unsigned h = 0;
        int won = 0, need = 0;
        if (act) {
            l_g = s_map[b][R.x];
            r_g = s_map[b][R.y];
            ls_g = (R.z >= 0) ? s_map[b][R.z] : R.z;
            rs_g = (R.w >= 0) ? s_map[b][R.w] : R.w;
            key = (l_g << HBITS) | r_g;
            h = hash0(key);
            need = 1;
        }
        while (__any(need)) {
            if (need) {
                int prev = atomicCAS(&s_hk[h], -1, key);
                if (prev == -1) { won = 1; need = 0; }
                else if (prev == key) { need = 0; }
                else { h = (h + 1) & HMASK; }
            }
        }
        unsigned long long actmask = __ballot(act != 0);
        unsigned long long winmask = __ballot(won != 0);
        unsigned long long below = (1ull << b) - 1ull;
        int ar = __popcll(actmask & below);
        int nact = __popcll(actmask);
        int newc = __popcll(winmask);
        if (won) {
            nid = Ncur + __popcll(winmask & below);
            s_hv[h] = nid;
        }
        __syncthreads();
        if (act && !won) nid = s_hv[h];
        if (won) newsrc[nid - N0] = (b << 6) | it;
        if (act) {
            int o1 = Tcur + ar;
            targets[o1 * 3 + 0] = l_g;
            targets[o1 * 3 + 1] = ls_g;
            targets[o1 * 3 + 2] = r_g;
            int o2 = Tcur + nact + ar;
            targets[o2 * 3 + 0] = r_g;
            targets[o2 * 3 + 1] = l_g;
            targets[o2 * 3 + 2] = rs_g;
            s_map[b][64 + it] = nid;
        }
        Ncur += newc;
        Tcur += 2 * nact;
        R = Rn;
    }
    if (b == 0) { meta[2] = Ncur; meta[3] = Tcur; meta[4] = Ncur - N0; }
}

// ---- pass 3: scatter composed rows + append eos/sos (block 4032) ----

__global__ __launch_bounds__(64) void materialize_kernel(
    const float* __restrict__ rowfeats, const int* __restrict__ newsrc,
    const int* __restrict__ meta, float* __restrict__ feats,
    const float* __restrict__ eos, const float* __restrict__ sos) {
    int g = blockIdx.x;
    int lane = threadIdx.x;
    if (g == 4032) {
        int n = meta[2];
        ((float4*)(feats + (size_t)n * 256))[lane] = ((const float4*)eos)[lane];
        ((float4*)(feats + (size_t)(n + 1) * 256))[lane] = ((const float4*)sos)[lane];
        return;
    }
    if (g >= meta[4]) return;
    int pk = newsrc[g];
    int b = pk >> 6, it = pk & 63;
    int N0 = meta[1];
    ((float4*)(feats + (size_t)(N0 + g) * 256))[lane] =
        ((const float4*)(rowfeats + ((size_t)b * 63 + it) * 256))[lane];
}

// ---- fused: bf16 fragment-major convert (blocks 0..1023) | out rows +
// target logits (blocks 1024..3039) ----
__global__ __launch_bounds__(256) void convout_kernel(
    const float* __restrict__ feats, const int* __restrict__ targets,
    const int* __restrict__ meta, const float* __restrict__ comp_l,
    const float* __restrict__ comp_r, const float* __restrict__ cb,
    short8* __restrict__ fhT, unsigned short* __restrict__ oh,
    float* __restrict__ tdot) {
    if (blockIdx.x < 1024) {
        int g = blockIdx.x * 256 + threadIdx.x;
        int tile = g >> 9, rem = g & 511;
        int ks = rem >> 6, lane64 = rem & 63;
        int kq = lane64 >> 4, col = lane64 & 15;
        int row = tile * 16 + col;
        int e0 = (ks * 4 + kq) * 8;
        const float4* src = (const float4*)(feats + (size_t)row * 256 + e0);
        float4 v0 = src[0], v1 = src[1];
        short8 o;
        o[0] = (short)f2bf(v0.x); o[1] = (short)f2bf(v0.y);
        o[2] = (short)f2bf(v0.z); o[3] = (short)f2bf(v0.w);
        o[4] = (short)f2bf(v1.x); o[5] = (short)f2bf(v1.y);
        o[6] = (short)f2bf(v1.z); o[7] = (short)f2bf(v1.w);
        fhT[g] = o;
        return;
    }
    int T = meta[3];
    int Ntot = meta[2] + 2;
    int t = (blockIdx.x - 1024) * 4 + (threadIdx.x >> 6);
    if (t >= T) return;
    int lane = threadIdx.x & 63;
    int c0 = 4 * (lane & 3);
    float4 sl4 = make_float4(1.f / (1.f + __expf(-comp_l[c0])),
                             1.f / (1.f + __expf(-comp_l[c0 + 1])),
                             1.f / (1.f + __expf(-comp_l[c0 + 2])),
                             1.f / (1.f + __expf(-comp_l[c0 + 3])));
    float4 sr4 = make_float4(1.f / (1.f + __expf(-comp_r[c0])),
                             1.f / (1.f + __expf(-comp_r[c0 + 1])),
                             1.f / (1.f + __expf(-comp_r[c0 + 2])),
                             1.f / (1.f + __expf(-comp_r[c0 + 3])));
    float4 cb4 = make_float4(cb[c0], cb[c0 + 1], cb[c0 + 2], cb[c0 + 3]);
    int t0 = targets[t * 3 + 0];
    int i1 = targets[t * 3 + 1], i2 = targets[t * 3 + 2];
    if (i1 < 0) i1 += Ntot;
    if (i2 < 0) i2 += Ntot;
    float4 a = ((const float4*)(feats + (size_t)i1 * 256))[lane];
    float4 b = ((const float4*)(feats + (size_t)i2 * 256))[lane];
    float4 ft = ((const float4*)(feats + (size_t)t0 * 256))[lane];
    float4 v;
    v.x = a.x * sl4.x + b.x * sr4.x + cb4.x;
    v.y = a.y * sl4.y + b.y * sr4.y + cb4.y;
    v.z = a.z * sl4.z + b.z * sr4.z + cb4.z;
    v.w = a.w * sl4.w + b.w * sr4.w + cb4.w;
    float d = v.x * ft.x + v.y * ft.y + v.z * ft.z + v.w * ft.w;
#pragma unroll
    for (int off = 32; off >= 1; off >>= 1) d += __shfl_down(d, off);
    if (lane == 0) tdot[t] = d;
    ushort4 h;
    h.x = f2bf(v.x * LOG2E); h.y = f2bf(v.y * LOG2E);
    h.z = f2bf(v.z * LOG2E); h.w = f2bf(v.w * LOG2E);
    ((ushort4*)(oh + (size_t)t * 256))[lane] = h;
}

// ---- loss: M=64/block, nq split, 126 x NSLAB grid; defer-max (THR=32);
// double-buffered LDS B staging: one barrier per step. ----
__global__ __launch_bounds__(512) void loss_mfma_kernel(
    const short8* __restrict__ fhT, const unsigned short* __restrict__ oh,
    const int* __restrict__ meta, float2* __restrict__ partial) {
    __shared__ short8 lds_b[2][1024];       // 32 KB: double-buffered tile pair
    __shared__ float s_m[64][2], s_s[64][2];
    int T = meta[3];
    int Ntot = meta[2] + 2;
    int row0 = blockIdx.x * 64;
    if (row0 >= T) return;
    int slab = blockIdx.y;
    int P = (Ntot + 32 * NSLAB - 1) / (32 * NSLAB);
    int cstart = slab * (P << 5);
    int cend = min(Ntot, cstart + (P << 5));
    int tid = threadIdx.x, lane = tid & 63, w = tid >> 6;
    int mq = w >> 1, nq = w & 1;
    int mrow = row0 + mq * 16 + (lane & 15);
    int kq = lane >> 4;
    const short8* pah = (const short8*)(oh + (size_t)mrow * 256);
    short8 Ah[8];
#pragma unroll
    for (int ks = 0; ks < 8; ++ks) Ah[ks] = pah[ks * 4 + kq];
    float m0 = -1e30f, m1 = -1e30f, m2 = -1e30f, m3 = -1e30f;
    float s0 = 0.f, s1 = 0.f, s2 = 0.f, s3 = 0.f;
    int cur = 0;
    if (cstart < cend) {
        const short8* sp = fhT + ((size_t)(cstart >> 4)) * 512;
        lds_b[0][tid] = sp[tid];
        lds_b[0][tid + 512] = sp[tid + 512];
        __syncthreads();
    }
    for (int nb = cstart; nb < cend; nb += 32) {
        short8 g0, g1;
        bool more = (nb + 32) < cend;
        if (more) {
            const short8* sn = fhT + ((size_t)((nb + 32) >> 4)) * 512;
            g0 = sn[tid];
            g1 = sn[tid + 512];
        }
        const short8* pb = &lds_b[cur][nq * 512];
        f32x4 a0 = {0.f, 0.f, 0.f, 0.f}, a1 = a0;
#pragma unroll
        for (int ks = 0; ks < 4; ++ks) {
            a0 = __builtin_amdgcn_mfma_f32_16x16x32_bf16(Ah[ks], pb[ks * 64 + lane], a0, 0, 0, 0);
            a1 = __builtin_amdgcn_mfma_f32_16x16x32_bf16(Ah[ks + 4], pb[(ks + 4) * 64 + lane], a1, 0, 0, 0);
        }
        int col = nb + nq * 16 + (lane & 15);
        bool cv = col < cend;
        float v0 = cv ? (a0[0] + a1[0]) : -INFINITY;   // log2-domain
        float v1 = cv ? (a0[1] + a1[1]) : -INFINITY;
        float v2 = cv ? (a0[2] + a1[2]) : -INFINITY;
        float v3 = cv ? (a0[3] + a1[3]) : -INFINITY;
        float d0 = v0 - m0, d1 = v1 - m1, d2 = v2 - m2, d3 = v3 - m3;
        if (d0 > 32.f) { s0 = s0 * exp2f(-d0) + 1.f; m0 = v0; } else s0 += exp2f(d0);
        if (d1 > 32.f) { s1 = s1 * exp2f(-d1) + 1.f; m1 = v1; } else s1 += exp2f(d1);
        if (d2 > 32.f) { s2 = s2 * exp2f(-d2) + 1.f; m2 = v2; } else s2 += exp2f(d2);
        if (d3 > 32.f) { s3 = s3 * exp2f(-d3) + 1.f; m3 = v3; } else s3 += exp2f(d3);
        if (more) {
            lds_b[cur ^ 1][tid] = g0;
            lds_b[cur ^ 1][tid + 512] = g1;
            __syncthreads();
            cur ^= 1;
        }
    }
#pragma unroll
    for (int off = 1; off < 16; off <<= 1) {
        float mo, so, mn;
        mo = __shfl_xor(m0, off); so = __shfl_xor(s0, off);
        mn = fmaxf(m0, mo); s0 = s0 * exp2f(m0 - mn) + so * exp2f(mo - mn); m0 = mn;
        mo = __shfl_xor(m1, off); so = __shfl_xor(s1, off);
        mn = fmaxf(m1, mo); s1 = s1 * exp2f(m1 - mn) + so * exp2f(mo - mn); m1 = mn;
        mo = __shfl_xor(m2, off); so = __shfl_xor(s2, off);
        mn = fmaxf(m2, mo); s2 = s2 * exp2f(m2 - mn) + so * exp2f(mo - mn); m2 = mn;
        mo = __shfl_xor(m3, off); so = __shfl_xor(s3, off);
        mn = fmaxf(m3, mo); s3 = s3 * exp2f(m3 - mn) + so * exp2f(mo - mn); m3 = mn;
    }
    if ((lane & 15) == 0) {
        int rbase = mq * 16 + kq * 4;
        s_m[rbase + 0][nq] = m0; s_s[rbase + 0][nq] = s0;
        s_m[rbase + 1][nq] = m1; s_s[rbase + 1][nq] = s1;
        s_m[rbase + 2][nq] = m2; s_s[rbase + 2][nq] = s2;
        s_m[rbase + 3][nq] = m3; s_s[rbase + 3][nq] = s3;
    }
    __syncthreads();
    if (tid < 64) {
        float ma = s_m[tid][0], mb = s_m[tid][1];
        float mn = fmaxf(ma, mb);
        float ss = s_s[tid][0] * exp2f(ma - mn) + s_s[tid][1] * exp2f(mb - mn);
        partial[(size_t)slab * NMAX + row0 + tid] = make_float2(mn, ss);
    }
}

// ---- combine + finalize: one block, no atomics ----
__global__ __launch_bounds__(1024) void combine_kernel(
    const float2* __restrict__ partial, const float* __restrict__ tdot,
    const int* __restrict__ meta, float* __restrict__ out) {
    __shared__ float red[16];
    int T = meta[3];
    float loss = 0.f;
    for (int r = threadIdx.x; r < T; r += 1024) {
        float2 ps[NSLAB];
        float mn = -1e30f;
#pragma unroll
        for (int s = 0; s < NSLAB; ++s) {
            ps[s] = partial[(size_t)s * NMAX + r];
            mn = fmaxf(mn, ps[s].x);
        }
        float ss = 0.f;
#pragma unroll
        for (int s = 0; s < NSLAB; ++s) ss += ps[s].y * exp2f(ps[s].x - mn);
        loss += (mn + __log2f(ss)) * LN2 - tdot[r];
    }
#pragma unroll
    for (int off = 32; off >= 1; off >>= 1) loss += __shfl_down(loss, off);
    if ((threadIdx.x & 63) == 0) red[threadIdx.x >> 6] = loss;
    __syncthreads();
    if (threadIdx.x < 16) {
        loss = red[threadIdx.x];
#pragma unroll
        for (int off = 8; off >= 1; off >>= 1) loss += __shfl_down(loss, off);
        if (threadIdx.x == 0) out[0] = loss / (float)T;
    }
}

extern "C" void kernel_launch(void* const* d_in, const int* in_sizes, int n_in,
                              void* d_out, int out_size, void* d_ws, size_t ws_size,
                              hipStream_t stream) {
    const int* x = (const int*)d_in[0];
    const float* emb = (const float*)d_in[1];
    const float* comp_l = (const float*)d_in[2];
    const float* comp_r = (const float*)d_in[3];
    const float* cb = (const float*)d_in[4];
    const float* sos = (const float*)d_in[5];
    const float* eos = (const float*)d_in[6];
    float* out = (float*)d_out;

    float* feats = (float*)d_ws;                   // 8192*256
    float* norms = feats + (size_t)NMAX * 256;     // 8192
    int* index_g = (int*)(norms + NMAX);           // 4096
    float* cos_g = (float*)(index_g + 4096);       // 4096
    int* tokens = (int*)(cos_g + 4096);            // 4096
    int* targets = tokens + 4096;                  // 8192*3
    int* meta = targets + NMAX * 3;                // 64
    float* tdot = (float*)(meta + 64);             // 8192
    float2* partial = (float2*)(tdot + NMAX);      // NSLAB*8192 float2
    int4* rec = (int4*)(partial + NSLAB * NMAX);   // 64*63 int4
    int* newsrc = (int*)(rec + 64 * 63);           // 4096
    float* rowfeats = (float*)(newsrc + 4096);     // 64*63*256
    short8* fhT = (short8*)(rowfeats + (size_t)64 * 63 * 256);   // NMAX*32 short8
    unsigned short* oh = (unsigned short*)(fhT + (size_t)NMAX * 32);

    prep_kernel<<<1, 1024, 0, stream>>>(x, tokens, meta, index_g);
    prefeats_kernel<<<8128, 64, 0, stream>>>(emb, tokens, meta, index_g,
                                             feats, norms, cos_g);
    treebuild_kernel<<<64, 64, 0, stream>>>(feats, norms, index_g, cos_g,
                                            rowfeats, rec, comp_l, comp_r, cb);
    idassign_kernel<<<1, 64, 0, stream>>>(rec, index_g, targets, meta, newsrc);
    materialize_kernel<<<4033, 64, 0, stream>>>(rowfeats, newsrc, meta, feats, eos, sos);
    convout_kernel<<<3040, 256, 0, stream>>>(feats, targets, meta, comp_l, comp_r,
                                             cb, fhT, oh, tdot);
    loss_mfma_kernel<<<dim3(126, NSLAB), 512, 0, stream>>>(fhT, oh, meta, partial);
    combine_kernel<<<1, 1024, 0, stream>>>(partial, tdot, meta, out);
}